// Round 9
// baseline (877.768 us; speedup 1.0000x reference)
//
#include <hip/hip_runtime.h>
#include <math.h>

// ExpertGate — np.einsum-bitwise replication; LDS-FREE main loop.
//
// CORRECTNESS CONTRACT (passed R2/R3/R5/R7): per (token, expert):
//   - 4 accumulator chains (k mod 4), packed as v2f components (per-component
//     VOP3P rounding == scalar); k consumed in groups of 16 ASCENDING; quads
//     within a group processed j = 3,2,1,0; mul/add separately rounded, never
//     fused (#pragma clang fp contract(off); pk ops are inline asm = immune)
//   - final reduce (c0+c1)+(c2+c3); sigmoid 1/(1+exp(-z)) fp32 with
//     correctly-rounded fp32 exp (via double); top-8 ties -> lower index
//
// R8 POST-MORTEM (5-run synthesis): VALU-busy invariant ~73us; R2/R5/R7 are
// LDS-READ-THROUGHPUT-bound (6.4-10.7 GB through the DS pipe = 123-205us at
// 85 B/cyc/CU — matches 162/190/167 measured). R8 cut DS bytes but collapsed
// to 1 wave/SIMD (LDS 75KB + VGPR 140 broke its ping-pong). THIS ROUND:
//   - NO LDS, NO barriers in the K loop: X and W stream global->reg.
//     X: 4 distinct rows/wave-inst (16-lane dup, TA-coalesced), each row
//     fetched once chip-wide (134 MB, ~21us). W: L2/L3-resident 512 KB.
//   - ping-pong dbuf (XA/XB, WA/WB): prefetch group g+1 issued around
//     compute of g (512+ cyc pk per group covers L2/L3 latency).
//   - ~240 VGPR @ __launch_bounds__(256,2): grid 512 = 2 blocks/CU =
//     2 waves/SIMD (grid-limited anyway; VGPR 256 is the natural budget).
//   - last-group prefetch clamps to k=0 (in-bounds, values discarded).

#pragma clang fp contract(off)

#define D_DIM 2048
#define E_DIM 64
#define TOPK 8
#define TM 32               // tokens per block
#define NGT 128             // 16-k groups total (2048/16)
#define SCS 65

typedef float v2f __attribute__((ext_vector_type(2)));

static __device__ __forceinline__ v2f pk_mul(v2f a, v2f b) {
    v2f d;
    asm("v_pk_mul_f32 %0, %1, %2" : "=v"(d) : "v"(a), "v"(b));
    return d;
}
static __device__ __forceinline__ v2f pk_add(v2f a, v2f b) {
    v2f d;
    asm("v_pk_add_f32 %0, %1, %2" : "=v"(d) : "v"(a), "v"(b));
    return d;
}

// load one 16-k group (X: 2 tokens, W: 4 experts) at float-offset koff
#define LOAD_G(XR, WR, koff)                                                   \
    {                                                                          \
        _Pragma("unroll")                                                      \
        for (int j = 0; j < 4; ++j) {                                          \
            XR[0][j] = *reinterpret_cast<const float4*>(xr0 + (koff) + 4 * j); \
            XR[1][j] = *reinterpret_cast<const float4*>(xr1 + (koff) + 4 * j); \
        }                                                                      \
        _Pragma("unroll")                                                      \
        for (int e = 0; e < 4; ++e)                                            \
            _Pragma("unroll")                                                  \
            for (int j = 0; j < 4; ++j)                                        \
                WR[e][j] = *reinterpret_cast<const float4*>(                   \
                    wr[e] + (koff) + 4 * j);                                   \
    }

// one 16-k group for the 2x4 (token,expert) tile; quads j = 3,2,1,0
#define COMPUTE_G(XR, WR)                                                      \
    {                                                                          \
        _Pragma("unroll")                                                      \
        for (int j = 3; j >= 0; --j) {                                         \
            _Pragma("unroll")                                                  \
            for (int i = 0; i < 2; ++i) {                                      \
                const v2f xlo = *reinterpret_cast<const v2f*>(&XR[i][j].x);    \
                const v2f xhi = *reinterpret_cast<const v2f*>(&XR[i][j].z);    \
                _Pragma("unroll")                                              \
                for (int e = 0; e < 4; ++e) {                                  \
                    const v2f wlo = *reinterpret_cast<const v2f*>(&WR[e][j].x);\
                    const v2f whi = *reinterpret_cast<const v2f*>(&WR[e][j].z);\
                    c01[i][e] = pk_add(c01[i][e], pk_mul(xlo, wlo));           \
                    c23[i][e] = pk_add(c23[i][e], pk_mul(xhi, whi));           \
                }                                                              \
            }                                                                  \
        }                                                                      \
    }

__global__ __launch_bounds__(256, 2) void expert_gate_kernel(
    const float* __restrict__ x,      // (N, 2048)
    const float* __restrict__ w,      // (64, 2048)
    const float* __restrict__ bias,   // (64,)
    float* __restrict__ out,          // N*8 weights, then N*8 indices-as-float
    int N)
{
#pragma clang fp contract(off)
    __shared__ float Sc[TM * SCS];    // 8.3 KB — epilogue only

    const int t    = threadIdx.x;
    const int tx   = t & 15;          // experts tx + 16e
    const int ty   = t >> 4;          // tokens ty and ty+16
    const int tok0 = blockIdx.x * TM;
    const int lane = t & 63;
    const float my_bias = bias[lane];

    // ---- operand row pointers (held for the whole kernel) ----
    const float* xr0 = &x[(size_t)(tok0 + ty) * D_DIM];
    const float* xr1 = &x[(size_t)(tok0 + 16 + ty) * D_DIM];
    const float* wr[4];
    #pragma unroll
    for (int e = 0; e < 4; ++e)
        wr[e] = &w[(size_t)(tx + 16 * e) * D_DIM];

    // acc: c01[i][e]=(chain0,chain1), c23[i][e]=(chain2,chain3)
    v2f c01[2][4], c23[2][4];
    #pragma unroll
    for (int i = 0; i < 2; ++i)
        #pragma unroll
        for (int e = 0; e < 4; ++e) { c01[i][e] = (v2f)(0.f); c23[i][e] = (v2f)(0.f); }

    float4 XA[2][4], XB[2][4];        // 16 float4
    float4 WA[4][4], WB[4][4];        // 32 float4

    LOAD_G(XA, WA, 0);                // group 0

    for (int gp = 0; gp < NGT / 2; ++gp) {
        const int kB = (2 * gp + 1) << 4;            // odd group -> B
        LOAD_G(XB, WB, kB);
        COMPUTE_G(XA, WA);                           // group 2gp
        // next even group -> A; clamp to 0 on the last iteration (in-bounds,
        // values never used — avoids reading past the end of x / w)
        const int kA = (gp + 1 < NGT / 2) ? ((2 * gp + 2) << 4) : 0;
        LOAD_G(XA, WA, kA);
        COMPUTE_G(XB, WB);                           // group 2gp+1
    }

    // ---- finalize: (c0+c1)+(c2+c3), fp32 sigmoid exactly like np ----
    #pragma unroll
    for (int i = 0; i < 2; ++i) {
        #pragma unroll
        for (int e = 0; e < 4; ++e) {
            float z = __fadd_rn(__fadd_rn(c01[i][e].x, c01[i][e].y),
                                __fadd_rn(c23[i][e].x, c23[i][e].y));
            float ez = (float)exp(-(double)z);   // correctly-rounded fp32 exp
            float sg = __fdiv_rn(1.0f, __fadd_rn(1.0f, ez));
            Sc[(ty + 16 * i) * SCS + (tx + 16 * e)] = sg;
        }
    }
    __syncthreads();

    // ---- top-8 per token: lane == expert; each wave handles 8 tokens ----
    const int wave = t >> 6;  // 0..3
    for (int r = 0; r < 8; ++r) {
        const int tok = wave * 8 + r;
        const float sg = Sc[tok * SCS + lane];   // original fp32 score
        float rv = __fadd_rn(sg, my_bias);       // routing score
        float outw = 0.f;
        int   outi = 0;
        float ssum = 0.f;
        #pragma unroll
        for (int sel = 0; sel < TOPK; ++sel) {
            float vv = rv;
            int   vi = lane;
            // 64-lane butterfly lexicographic max (ties -> lower index, = top_k)
            #pragma unroll
            for (int off = 1; off < 64; off <<= 1) {
                float ov = __shfl_xor(vv, off);
                int   oi = __shfl_xor(vi, off);
                if (ov > vv || (ov == vv && oi < vi)) { vv = ov; vi = oi; }
            }
            float cs = __shfl(sg, vi);  // un-biased score of winner
            ssum = __fadd_rn(ssum, cs);
            if (lane == sel) { outw = cs; outi = vi; }
            if (lane == vi) rv = -INFINITY;
        }
        if (lane < TOPK) {
            const size_t base = (size_t)(tok0 + tok) * TOPK + lane;
            out[base] = __fmul_rn(__fdiv_rn(outw, __fadd_rn(ssum, 1e-8f)), 2.5f);
            out[(size_t)N * TOPK + base] = (float)outi;
        }
    }
}

extern "C" void kernel_launch(void* const* d_in, const int* in_sizes, int n_in,
                              void* d_out, int out_size, void* d_ws, size_t ws_size,
                              hipStream_t stream) {
    const float* x    = (const float*)d_in[0];
    const float* w    = (const float*)d_in[1];
    const float* bias = (const float*)d_in[2];
    float* out = (float*)d_out;
    const int N = in_sizes[0] / D_DIM;  // 16384
    const int grid = N / TM;            // 512
    expert_gate_kernel<<<grid, 256, 0, stream>>>(x, w, bias, out, N);
}